// Round 9
// baseline (173.814 us; speedup 1.0000x reference)
//
#include <hip/hip_runtime.h>
#include <stdint.h>

// ChamferDistance2D: B=8, N=M=8192, fp32, scalar out.
// R9: algorithmic — exact grid-bucketed nearest neighbor, O(N*M) -> O(N*k).
// R8 established the brute-force VALU path is at its empirical issue ceiling
// (65us at ~80% of m07's measured v_fma rate); MFMA path measured slower (R6).
// Pipeline: histogram points into a 128x128 grid over [-4.25,4.25]^2
// (h = 8.5/128 = 0.06640625, exact), exclusive-scan per (side,batch) grid,
// counting-sort scatter, then per-query expanding Chebyshev-ring search over
// the OPPOSITE side's cells. Exactness: projection onto the grid box is
// 1-Lipschitz, so any point in an unscanned cell (ring >= c+1) has distance
// >= c*h; stop when best_sq <= (c*h)^2. Outliers clamped to edge cells are
// covered by the same argument. Queries walk in sorted order -> wave lanes
// share cells (coherent rings, L1-shared candidate loads). Typical NN dist
// (0.014..0.07) < h, so most queries stop after ring 1 (~26 candidates).
// ws: counts 1MB @0, start 1MB @1M, cursor 1MB @2M, sorted 1MB @3M.

#define BATCH 8
#define NPTS  8192
#define TPB   256
#define GRID  128
#define G2    (GRID * GRID)
#define BOX   4.25f
#define H     0.06640625f        // 8.5/128, exact in binary
#define NSB   (2 * BATCH)        // side*BATCH+b grids

__device__ inline int cellof(float v) {
    int c = (int)((v + BOX) * (1.0f / H));
    return min(max(c, 0), GRID - 1);
}

// grid = 2*B*N/TPB = 512
__global__ void hist_k(const float2* __restrict__ p1, const float2* __restrict__ p2,
                       int* __restrict__ counts) {
    int g = blockIdx.x * TPB + threadIdx.x;
    int side = g >> 16, b = (g >> 13) & 7, i = g & (NPTS - 1);
    float2 P = (side ? p2 : p1)[(size_t)b * NPTS + i];
    int cell = cellof(P.y) * GRID + cellof(P.x);
    atomicAdd(&counts[(side * BATCH + b) * G2 + cell], 1);
}

// grid = 16 blocks; block sb scans its 16384-cell grid -> start (excl prefix), cursor copy
__global__ __launch_bounds__(TPB) void prefix_k(const int* __restrict__ counts,
                                                int* __restrict__ start,
                                                int* __restrict__ cursor) {
    __shared__ int psum[TPB];
    const int CPT = G2 / TPB;                    // 64 cells per thread
    int base = blockIdx.x * G2;
    int t = threadIdx.x;
    int s = 0;
    for (int u = 0; u < CPT; ++u) s += counts[base + t * CPT + u];
    psum[t] = s;
    __syncthreads();
    for (int off = 1; off < TPB; off <<= 1) {    // inclusive Hillis-Steele
        int v = (t >= off) ? psum[t - off] : 0;
        __syncthreads();
        psum[t] += v;
        __syncthreads();
    }
    int run = psum[t] - s;                       // exclusive base for this thread
    for (int u = 0; u < CPT; ++u) {
        int idx = base + t * CPT + u;
        int c = counts[idx];
        start[idx] = run;
        cursor[idx] = run;
        run += c;
    }
}

// grid = 512
__global__ void scatter_k(const float2* __restrict__ p1, const float2* __restrict__ p2,
                          int* __restrict__ cursor, float2* __restrict__ sorted) {
    int g = blockIdx.x * TPB + threadIdx.x;
    int side = g >> 16, b = (g >> 13) & 7, i = g & (NPTS - 1);
    float2 P = (side ? p2 : p1)[(size_t)b * NPTS + i];
    int cell = cellof(P.y) * GRID + cellof(P.x);
    int sb = side * BATCH + b;
    int pos = atomicAdd(&cursor[sb * G2 + cell], 1);
    sorted[(size_t)sb * NPTS + pos] = P;
}

// grid = 512. One thread per query; expanding-ring exact NN; block-sum -> atomicAdd.
__global__ __launch_bounds__(TPB) void query_k(const float2* __restrict__ sorted,
                                               const int* __restrict__ start,
                                               const int* __restrict__ counts,
                                               float* __restrict__ out) {
    int g = blockIdx.x * TPB + threadIdx.x;
    int dir = g >> 16, b = (g >> 13) & 7, i = g & (NPTS - 1);

    float2 q = sorted[((size_t)(dir * BATCH + b)) * NPTS + i];   // queries in sorted order
    int tg = (1 - dir) * BATCH + b;                              // opposite side's grid
    const float2* __restrict__ pts = sorted + (size_t)tg * NPTS;
    const int* __restrict__ st = start + tg * G2;
    const int* __restrict__ ct = counts + tg * G2;

    int cx = cellof(q.x), cy = cellof(q.y);
    float best = 3.0e38f;

    auto scan = [&](int cell_lo, int cell_hi) {   // contiguous cell range (row-major)
        int s = st[cell_lo];
        int e = st[cell_hi] + ct[cell_hi];
        for (int k = s; k < e; ++k) {
            float2 p = pts[k];
            float dx = q.x - p.x, dy = q.y - p.y;
            best = fminf(best, fmaf(dx, dx, dy * dy));
        }
    };

    scan(cy * GRID + cx, cy * GRID + cx);         // ring 0: own cell
    int cmax = max(max(cx, GRID - 1 - cx), max(cy, GRID - 1 - cy));
    for (int c = 1;; ++c) {
        int xlo = max(cx - c, 0), xhi = min(cx + c, GRID - 1);
        if (cy - c >= 0)        scan((cy - c) * GRID + xlo, (cy - c) * GRID + xhi);
        if (cy + c <= GRID - 1) scan((cy + c) * GRID + xlo, (cy + c) * GRID + xhi);
        int ylo = max(cy - c + 1, 0), yhi = min(cy + c - 1, GRID - 1);
        if (cx - c >= 0)
            for (int y = ylo; y <= yhi; ++y) scan(y * GRID + cx - c, y * GRID + cx - c);
        if (cx + c <= GRID - 1)
            for (int y = ylo; y <= yhi; ++y) scan(y * GRID + cx + c, y * GRID + cx + c);
        float bd = (float)c * H;                  // unscanned points are >= c*h away
        if (best <= bd * bd || c >= cmax) break;
    }

    // block sum of best -> single atomic per block
    float d = best;
#pragma unroll
    for (int off = 32; off > 0; off >>= 1)
        d += __shfl_down(d, off, 64);
    __shared__ float wsum[TPB / 64];
    int lane = threadIdx.x & 63, w = threadIdx.x >> 6;
    if (lane == 0) wsum[w] = d;
    __syncthreads();
    if (threadIdx.x == 0)
        atomicAdd(out, (wsum[0] + wsum[1] + wsum[2] + wsum[3]) * (1.0f / NPTS));
}

extern "C" void kernel_launch(void* const* d_in, const int* in_sizes, int n_in,
                              void* d_out, int out_size, void* d_ws, size_t ws_size,
                              hipStream_t stream) {
    const float2* p1 = (const float2*)d_in[0];
    const float2* p2 = (const float2*)d_in[1];
    float* out = (float*)d_out;

    char* ws = (char*)d_ws;
    int*    counts = (int*)(ws);
    int*    start  = (int*)(ws + (size_t)1 * 1024 * 1024);
    int*    cursor = (int*)(ws + (size_t)2 * 1024 * 1024);
    float2* sorted = (float2*)(ws + (size_t)3 * 1024 * 1024);
    // 4 MB total (>=33.5 MB proven available)

    hipMemsetAsync(counts, 0, (size_t)NSB * G2 * sizeof(int), stream);
    hipMemsetAsync(out, 0, sizeof(float), stream);

    hist_k<<<2 * BATCH * NPTS / TPB, TPB, 0, stream>>>(p1, p2, counts);
    prefix_k<<<NSB, TPB, 0, stream>>>(counts, start, cursor);
    scatter_k<<<2 * BATCH * NPTS / TPB, TPB, 0, stream>>>(p1, p2, cursor, sorted);
    query_k<<<2 * BATCH * NPTS / TPB, TPB, 0, stream>>>(sorted, start, counts, out);
}